// Round 1
// baseline (195.728 us; speedup 1.0000x reference)
//
#include <hip/hip_runtime.h>

// E[b,k,d] = sum_n A[b,n,k] * R[b,n,k,d]
// B=16, N=8192, K=32, D=64, fp32 in/out.
// Memory-bound: R is 1.07 GB read once. Strategy: each block streams a
// contiguous n-chunk of R for one b; per n the K*D=2048-float slab is
// contiguous (8 KB), covered by 256 threads x 2 float4 quads each.
// Register accumulation over the chunk, atomicAdd epilogue into zeroed d_out.

#define B_ 16
#define N_ 8192
#define K_ 32
#define D_ 64
#define CHUNKS 64
#define CHUNK_N (N_ / CHUNKS)   // 128 n per block

__global__ __launch_bounds__(256)
void Aggregate_34840774705429_kernel(const float* __restrict__ A,
                                     const float* __restrict__ R,
                                     float* __restrict__ out) {
    const int blk = blockIdx.x;          // b * CHUNKS + c
    const int b  = blk / CHUNKS;
    const int c  = blk % CHUNKS;
    const int n0 = c * CHUNK_N;

    const int tid = threadIdx.x;
    // 512 float4 "quad positions" per (b,n) slab: p = k*16 + dq  (dq = d/4)
    const int p0 = tid;
    const int p1 = tid + 256;
    const int k0 = p0 >> 4;
    const int k1 = p1 >> 4;

    const float* __restrict__ Ab = A + (size_t)b * N_ * K_;
    const float4* __restrict__ Rb = (const float4*)(R + (size_t)b * N_ * K_ * D_);
    // quads per n-slab = K_*D_/4 = 512

    float4 acc0 = make_float4(0.f, 0.f, 0.f, 0.f);
    float4 acc1 = make_float4(0.f, 0.f, 0.f, 0.f);

    #pragma unroll 4
    for (int n = n0; n < n0 + CHUNK_N; ++n) {
        const float4* Rn = Rb + (size_t)n * 512;
        const float a0 = Ab[n * K_ + k0];
        const float a1 = Ab[n * K_ + k1];
        const float4 r0 = Rn[p0];
        const float4 r1 = Rn[p1];
        acc0.x = fmaf(a0, r0.x, acc0.x);
        acc0.y = fmaf(a0, r0.y, acc0.y);
        acc0.z = fmaf(a0, r0.z, acc0.z);
        acc0.w = fmaf(a0, r0.w, acc0.w);
        acc1.x = fmaf(a1, r1.x, acc1.x);
        acc1.y = fmaf(a1, r1.y, acc1.y);
        acc1.z = fmaf(a1, r1.z, acc1.z);
        acc1.w = fmaf(a1, r1.w, acc1.w);
    }

    float* __restrict__ Ob = out + (size_t)b * K_ * D_;
    // position p maps to float offset p*4 within the K*D slab
    atomicAdd(&Ob[p0 * 4 + 0], acc0.x);
    atomicAdd(&Ob[p0 * 4 + 1], acc0.y);
    atomicAdd(&Ob[p0 * 4 + 2], acc0.z);
    atomicAdd(&Ob[p0 * 4 + 3], acc0.w);
    atomicAdd(&Ob[p1 * 4 + 0], acc1.x);
    atomicAdd(&Ob[p1 * 4 + 1], acc1.y);
    atomicAdd(&Ob[p1 * 4 + 2], acc1.z);
    atomicAdd(&Ob[p1 * 4 + 3], acc1.w);
}

extern "C" void kernel_launch(void* const* d_in, const int* in_sizes, int n_in,
                              void* d_out, int out_size, void* d_ws, size_t ws_size,
                              hipStream_t stream) {
    const float* A = (const float*)d_in[0];
    const float* R = (const float*)d_in[1];
    float* out = (float*)d_out;

    // d_out is poisoned (0xAA) before timing and not re-poisoned between
    // replays; we accumulate via atomics, so zero it every call.
    hipMemsetAsync(out, 0, (size_t)out_size * sizeof(float), stream);

    dim3 grid(B_ * CHUNKS);
    dim3 block(256);
    Aggregate_34840774705429_kernel<<<grid, block, 0, stream>>>(A, R, out);
}

// Round 2
// 195.394 us; speedup vs baseline: 1.0017x; 1.0017x over previous
//
#include <hip/hip_runtime.h>

// E[b,k,d] = sum_n A[b,n,k] * R[b,n,k,d]
// B=16, N=8192, K=32, D=64, fp32 in/out.
// Memory-bound: R is 1.07 GB read once -> roofline ~173 us @ 6.3 TB/s.
// Each block streams a contiguous n-chunk of R for one b; per n the
// K*D=2048-float slab is contiguous (8 KB), covered by 256 threads x 2
// float4 quads. Register accumulation, atomicAdd epilogue into zeroed d_out.
// R loads are non-temporal (read-once; keep 16 MB A L2-resident).
// 2048 blocks = 8 blocks/CU = 32 waves/CU for full latency hiding.

#define B_ 16
#define N_ 8192
#define K_ 32
#define D_ 64
#define CHUNKS 128
#define CHUNK_N (N_ / CHUNKS)   // 64 n per block

typedef float f4 __attribute__((ext_vector_type(4)));

__global__ __launch_bounds__(256, 8)
void Aggregate_34840774705429_kernel(const float* __restrict__ A,
                                     const float* __restrict__ R,
                                     float* __restrict__ out) {
    const int blk = blockIdx.x;          // b * CHUNKS + c
    const int b  = blk / CHUNKS;
    const int c  = blk % CHUNKS;
    const int n0 = c * CHUNK_N;

    const int tid = threadIdx.x;
    // 512 float4 "quad positions" per (b,n) slab: p = k*16 + dq  (dq = d/4)
    const int p0 = tid;
    const int p1 = tid + 256;
    const int k0 = p0 >> 4;
    const int k1 = p1 >> 4;

    const float* __restrict__ Ab = A + (size_t)b * N_ * K_;
    const f4* __restrict__ Rb = (const f4*)(R + (size_t)b * N_ * K_ * D_);

    f4 acc0 = (f4)(0.f);
    f4 acc1 = (f4)(0.f);

    #pragma unroll 4
    for (int n = n0; n < n0 + CHUNK_N; ++n) {
        const f4* Rn = Rb + (size_t)n * 512;
        const float a0 = Ab[n * K_ + k0];
        const float a1 = Ab[n * K_ + k1];
        const f4 r0 = __builtin_nontemporal_load(Rn + p0);
        const f4 r1 = __builtin_nontemporal_load(Rn + p1);
        acc0 += a0 * r0;
        acc1 += a1 * r1;
    }

    float* __restrict__ Ob = out + (size_t)b * K_ * D_;
    atomicAdd(&Ob[p0 * 4 + 0], acc0.x);
    atomicAdd(&Ob[p0 * 4 + 1], acc0.y);
    atomicAdd(&Ob[p0 * 4 + 2], acc0.z);
    atomicAdd(&Ob[p0 * 4 + 3], acc0.w);
    atomicAdd(&Ob[p1 * 4 + 0], acc1.x);
    atomicAdd(&Ob[p1 * 4 + 1], acc1.y);
    atomicAdd(&Ob[p1 * 4 + 2], acc1.z);
    atomicAdd(&Ob[p1 * 4 + 3], acc1.w);
}

extern "C" void kernel_launch(void* const* d_in, const int* in_sizes, int n_in,
                              void* d_out, int out_size, void* d_ws, size_t ws_size,
                              hipStream_t stream) {
    const float* A = (const float*)d_in[0];
    const float* R = (const float*)d_in[1];
    float* out = (float*)d_out;

    // We accumulate via atomics; d_out must be zeroed every call.
    hipMemsetAsync(out, 0, (size_t)out_size * sizeof(float), stream);

    dim3 grid(B_ * CHUNKS);
    dim3 block(256);
    Aggregate_34840774705429_kernel<<<grid, block, 0, stream>>>(A, R, out);
}

// Round 3
// 191.935 us; speedup vs baseline: 1.0198x; 1.0180x over previous
//
#include <hip/hip_runtime.h>

// E[b,k,d] = sum_n A[b,n,k] * R[b,n,k,d]
// B=16, N=8192, K=32, D=64, fp32 in/out.
// Memory-bound: R is 1.07 GB read once. 5.6 TB/s reached; this round tests
// DRAM row locality: STRIDED n-assignment (n = c + i*CHUNKS) so the 128
// blocks of each b read CONSECUTIVE 8 KB slabs at any instant (16 contiguous
// moving fronts chip-wide) instead of 2048 scattered 512 KB streams.
// Register accumulation, atomicAdd epilogue into zeroed d_out.

#define B_ 16
#define N_ 8192
#define K_ 32
#define D_ 64
#define CHUNKS 128
#define CHUNK_N (N_ / CHUNKS)   // 64 n per block

typedef float f4 __attribute__((ext_vector_type(4)));

__global__ __launch_bounds__(256, 8)
void Aggregate_34840774705429_kernel(const float* __restrict__ A,
                                     const float* __restrict__ R,
                                     float* __restrict__ out) {
    const int blk = blockIdx.x;          // b * CHUNKS + c
    const int b  = blk / CHUNKS;
    const int c  = blk % CHUNKS;

    const int tid = threadIdx.x;
    // 512 float4 "quad positions" per (b,n) slab: p = k*16 + dq  (dq = d/4)
    const int p0 = tid;
    const int p1 = tid + 256;
    const int k0 = p0 >> 4;
    const int k1 = p1 >> 4;

    const float* __restrict__ Ab = A + (size_t)b * N_ * K_;
    const f4* __restrict__ Rb = (const f4*)(R + (size_t)b * N_ * K_ * D_);

    f4 acc0 = (f4)(0.f);
    f4 acc1 = (f4)(0.f);

    // strided n: block c handles n = c, c+CHUNKS, c+2*CHUNKS, ...
    #pragma unroll 4
    for (int i = 0; i < CHUNK_N; ++i) {
        const int n = c + i * CHUNKS;
        const f4* Rn = Rb + (size_t)n * 512;
        const float a0 = Ab[n * K_ + k0];
        const float a1 = Ab[n * K_ + k1];
        const f4 r0 = __builtin_nontemporal_load(Rn + p0);
        const f4 r1 = __builtin_nontemporal_load(Rn + p1);
        acc0 += a0 * r0;
        acc1 += a1 * r1;
    }

    float* __restrict__ Ob = out + (size_t)b * K_ * D_;
    atomicAdd(&Ob[p0 * 4 + 0], acc0.x);
    atomicAdd(&Ob[p0 * 4 + 1], acc0.y);
    atomicAdd(&Ob[p0 * 4 + 2], acc0.z);
    atomicAdd(&Ob[p0 * 4 + 3], acc0.w);
    atomicAdd(&Ob[p1 * 4 + 0], acc1.x);
    atomicAdd(&Ob[p1 * 4 + 1], acc1.y);
    atomicAdd(&Ob[p1 * 4 + 2], acc1.z);
    atomicAdd(&Ob[p1 * 4 + 3], acc1.w);
}

extern "C" void kernel_launch(void* const* d_in, const int* in_sizes, int n_in,
                              void* d_out, int out_size, void* d_ws, size_t ws_size,
                              hipStream_t stream) {
    const float* A = (const float*)d_in[0];
    const float* R = (const float*)d_in[1];
    float* out = (float*)d_out;

    // We accumulate via atomics; d_out must be zeroed every call.
    hipMemsetAsync(out, 0, (size_t)out_size * sizeof(float), stream);

    dim3 grid(B_ * CHUNKS);
    dim3 block(256);
    Aggregate_34840774705429_kernel<<<grid, block, 0, stream>>>(A, R, out);
}

// Round 4
// 187.349 us; speedup vs baseline: 1.0447x; 1.0245x over previous
//
#include <hip/hip_runtime.h>

// E[b,k,d] = sum_n A[b,n,k] * R[b,n,k,d]
// B=16, N=8192, K=32, D=64, fp32 in/out.
// Memory-bound: R is 1.07 GB read once (5.7 TB/s reached).
// This round: stage the block's A-slice (8 KB) into LDS once, so the inner
// loop issues ONLY the two R dwordx4 loads -> frees L1 miss-tracking slots
// and halves VMEM instruction count. Strided n kept (R2: +1.8%).
// Register accumulation, atomicAdd epilogue into zeroed d_out.

#define B_ 16
#define N_ 8192
#define K_ 32
#define D_ 64
#define CHUNKS 128
#define CHUNK_N (N_ / CHUNKS)   // 64 n per block

typedef float f4 __attribute__((ext_vector_type(4)));

__global__ __launch_bounds__(256, 8)
void Aggregate_34840774705429_kernel(const float* __restrict__ A,
                                     const float* __restrict__ R,
                                     float* __restrict__ out) {
    const int blk = blockIdx.x;          // b * CHUNKS + c
    const int b  = blk / CHUNKS;
    const int c  = blk % CHUNKS;

    const int tid = threadIdx.x;
    // 512 float4 "quad positions" per (b,n) slab: p = k*16 + dq  (dq = d/4)
    const int p0 = tid;
    const int p1 = tid + 256;
    const int k0 = p0 >> 4;
    const int k1 = p1 >> 4;

    const float* __restrict__ Ab = A + (size_t)b * N_ * K_;
    const f4* __restrict__ Rb = (const f4*)(R + (size_t)b * N_ * K_ * D_);

    // ---- stage A[b, c + i*CHUNKS, 0:32] for i in [0,64) into LDS (8 KB) ----
    // 2048 floats = 512 float4; thread t loads quads t and t+256.
    // quad q: row i = q>>3 (n = c + i*CHUNKS), col4 = q&7 (k-quad).
    __shared__ float lds_A[CHUNK_N * K_];
    {
        const f4* __restrict__ Ab4 = (const f4*)Ab;
        f4* __restrict__ L4 = (f4*)lds_A;
        const int q0 = tid;
        const int q1 = tid + 256;
        L4[q0] = Ab4[(size_t)(c + (q0 >> 3) * CHUNKS) * (K_ / 4) + (q0 & 7)];
        L4[q1] = Ab4[(size_t)(c + (q1 >> 3) * CHUNKS) * (K_ / 4) + (q1 & 7)];
    }
    __syncthreads();

    f4 acc0 = (f4)(0.f);
    f4 acc1 = (f4)(0.f);

    // strided n: block c handles n = c, c+CHUNKS, c+2*CHUNKS, ...
    #pragma unroll 4
    for (int i = 0; i < CHUNK_N; ++i) {
        const int n = c + i * CHUNKS;
        const f4* Rn = Rb + (size_t)n * 512;
        const float a0 = lds_A[i * K_ + k0];   // 16-lane broadcast, conflict-free
        const float a1 = lds_A[i * K_ + k1];
        const f4 r0 = __builtin_nontemporal_load(Rn + p0);
        const f4 r1 = __builtin_nontemporal_load(Rn + p1);
        acc0 += a0 * r0;
        acc1 += a1 * r1;
    }

    float* __restrict__ Ob = out + (size_t)b * K_ * D_;
    atomicAdd(&Ob[p0 * 4 + 0], acc0.x);
    atomicAdd(&Ob[p0 * 4 + 1], acc0.y);
    atomicAdd(&Ob[p0 * 4 + 2], acc0.z);
    atomicAdd(&Ob[p0 * 4 + 3], acc0.w);
    atomicAdd(&Ob[p1 * 4 + 0], acc1.x);
    atomicAdd(&Ob[p1 * 4 + 1], acc1.y);
    atomicAdd(&Ob[p1 * 4 + 2], acc1.z);
    atomicAdd(&Ob[p1 * 4 + 3], acc1.w);
}

extern "C" void kernel_launch(void* const* d_in, const int* in_sizes, int n_in,
                              void* d_out, int out_size, void* d_ws, size_t ws_size,
                              hipStream_t stream) {
    const float* A = (const float*)d_in[0];
    const float* R = (const float*)d_in[1];
    float* out = (float*)d_out;

    // We accumulate via atomics; d_out must be zeroed every call.
    hipMemsetAsync(out, 0, (size_t)out_size * sizeof(float), stream);

    dim3 grid(B_ * CHUNKS);
    dim3 block(256);
    Aggregate_34840774705429_kernel<<<grid, block, 0, stream>>>(A, R, out);
}